// Round 11
// baseline (122.164 us; speedup 1.0000x reference)
//
#include <hip/hip_runtime.h>
#include <type_traits>

#define EPS 1e-5f

typedef float f2 __attribute__((ext_vector_type(2)));
typedef float f4 __attribute__((ext_vector_type(4)));

// Broadcast a block-uniform load into an SGPR (scalars).
__device__ __forceinline__ float uload(const float* __restrict__ p) {
  return __int_as_float(__builtin_amdgcn_readfirstlane(__float_as_int(*p)));
}

__device__ __forceinline__ f2 fma2(f2 a, f2 b, f2 c) {
  return __builtin_elementwise_fma(a, b, c);
}
__device__ __forceinline__ f2 splat2(float s) { f2 r; r.x = s; r.y = s; return r; }

// ---------------------------------------------------------------------------
// K12: fused conv1(1->8)+ReLU+pool + conv2(4 used oc of 16)+ReLU+pool + sum.
// Block = (batch b, quarter q): pooled2 rows 8q..8q+7, 256 threads.
// Hard-won notes (r1-r21):
//  - conv1 reads x from GLOBAL. LDS xtile stride-2 reads = 1.06M conflict
//    cycles (r4). Never again.
//  - conv1 REGISTER prefetch is PERMANENTLY DEAD: r9/r11/r13/r15/r17 all
//    spilled. The 64-VGPR allocator target is immovable. Live state must
//    stay <= ONE 24-float xin buffer.
//  - r16: weights block-uniform -> SGPRs (s_load, zero VGPR cost). Freed
//    36 VGPRs, removed LDS staging + barrier + ~30K ds_read/block.
//    BEST: 117.9 us (reconfirmed r20), k12 < 43 us.
//  - r18: 576-thr one-task-per-thread REGRESSED (no intra-thread overlap).
//  - r19: width-32 __shfl for halo DIVERGED under graph replay. BANNED.
//  - r21 (this round): (a) interior/edge split — q in {1,2} has every
//    rok/vG/clamp provably true; if constexpr-fold them away behind a
//    wave-uniform branch (values unchanged -> bitwise-identical).
//    (b) round-2 residue tasks 512..575 spread 16-per-wave instead of
//    all on wave 0 (critical path 3 -> 2.25 tasks/wave).
//  - r14: occupancy NOT LDS-limited; per-block fixed cost dominates.
//  - r15: never hold xin across the conv2 phase (119 MB spill).
//  - pk_fma (r7) + conv2 two-named-buffer ic pipeline (r12) keepers.
//  - r10: tail fusion = ~30 us serialization; tail stays separate.
//    Harness d_ws fill (~44 us) + input restore (~11 us) are fixed.
// ---------------------------------------------------------------------------
__global__ __launch_bounds__(256, 4) void k12_fused(
    const float* __restrict__ x, const float* __restrict__ w1,
    const float* __restrict__ b1, const float* __restrict__ w2,
    const float* __restrict__ b2, float* __restrict__ partials) {
  __shared__ __align__(16) float p1[8][18][66];  // pooled1; col idx = col+1
  __shared__ float wred[4][4];

  const int q   = blockIdx.x & 3;
  const int b   = blockIdx.x >> 2;
  const int tid = threadIdx.x;
  const float* xb = x + (size_t)b * (128 * 128);

  // M: std::true_type = masked (image top/bottom edges possible),
  //    std::false_type = interior (all masks provably no-ops; folded).
  auto c1_load = [&](auto M, int pos, float xin[4][6]) {
    constexpr bool MASK = decltype(M)::value;
    const int gl = pos >> 5, i = pos & 31;
    const int G  = 16 * q - 1 + gl;
    const int xr0 = 2 * G - 1;
    const bool vG = MASK ? (((unsigned)G) < 64u) : true;
#pragma unroll
    for (int r = 0; r < 4; ++r) {
      const int row  = xr0 + r;
      const bool rok = MASK ? (vG && ((unsigned)row < 128u)) : true;
      const int rowc = MASK ? min(max(row, 0), 127) : row;
      const float* rp = xb + rowc * 128;
      const float le = rp[(i == 0) ? 0 : (4 * i - 1)];
      const f4 mid   = *(const f4*)(rp + 4 * i);        // 16B-aligned
      const float ri = rp[(i == 31) ? 127 : (4 * i + 4)];
      xin[r][0] = (rok && i != 0)  ? le    : 0.f;
      xin[r][1] = rok              ? mid.x : 0.f;
      xin[r][2] = rok              ? mid.y : 0.f;
      xin[r][3] = rok              ? mid.z : 0.f;
      xin[r][4] = rok              ? mid.w : 0.f;
      xin[r][5] = (rok && i != 31) ? ri    : 0.f;
    }
  };
  auto c1_compute = [&](auto M, int pos, const float xin[4][6]) {
    constexpr bool MASK = decltype(M)::value;
    const int gl = pos >> 5, i = pos & 31;
    const int G  = 16 * q - 1 + gl;
    const bool vG = MASK ? (((unsigned)G) < 64u) : true;
    // Two sequential oc-halves; weights are UNIFORM scalar loads (SGPRs).
#pragma unroll 1
    for (int g = 0; g < 2; ++g) {
      f2 wpx[9][2], bias[2];
#pragma unroll
      for (int k = 0; k < 9; ++k)
#pragma unroll
        for (int p = 0; p < 2; ++p) {
          const int oc = 4 * g + 2 * p;
          f2 wv;
          wv.x = w1[oc * 9 + k];        // uniform -> s_load
          wv.y = w1[(oc + 1) * 9 + k];  // uniform -> s_load
          wpx[k][p] = wv;
        }
      bias[0].x = b1[4 * g];     bias[0].y = b1[4 * g + 1];
      bias[1].x = b1[4 * g + 2]; bias[1].y = b1[4 * g + 3];
#pragma unroll
      for (int p = 0; p < 2; ++p)
#pragma unroll
        for (int h = 0; h < 2; ++h) {  // pooled col 2i+h
          f2 best = splat2(0.f);       // ReLU floor
#pragma unroll
          for (int dy = 0; dy < 2; ++dy)
#pragma unroll
            for (int dx = 0; dx < 2; ++dx) {
              f2 a = bias[p];
#pragma unroll
              for (int ky = 0; ky < 3; ++ky)
#pragma unroll
                for (int kx = 0; kx < 3; ++kx)
                  a = fma2(wpx[ky * 3 + kx][p],
                           splat2(xin[dy + ky][2 * h + dx + kx]), a);
              best.x = fmaxf(best.x, a.x);
              best.y = fmaxf(best.y, a.y);
            }
          const int oc0 = 4 * g + 2 * p;
          p1[oc0][gl][2 * i + 1 + h]     = vG ? best.x : 0.f;
          p1[oc0 + 1][gl][2 * i + 1 + h] = vG ? best.y : 0.f;
        }
    }
  };

  // zero p1's SAME-padding halo columns (disjoint from conv1's writes;
  // ordered vs conv2's reads by B1 — no extra barrier needed)
  if (tid >= 96 && tid < 240) {
    int t = tid - 96;
    int ic = t / 18, r = t % 18;
    p1[ic][r][0]  = 0.f;
    p1[ic][r][65] = 0.f;
  }

  // ---- conv1 + ReLU + pool, ALL 8 channels; task-0 loads first ----
  // Rounds: 0 = tasks tid, 1 = tid+256, 2 = 64 residue tasks spread
  // 16-per-wave (divergence-safe: no shuffles/barriers inside a task).
  const bool res  = (tid & 63) < 16;
  const int  pos2 = 512 + (tid >> 6) * 16 + (tid & 15);
  if (q == 1 || q == 2) {
    // interior: every mask provably true -> folded away
    {
      float xin0[4][6];
      c1_load(std::false_type{}, tid, xin0);
      c1_compute(std::false_type{}, tid, xin0);
    }
    {
      float xin[4][6];
      c1_load(std::false_type{}, tid + 256, xin);
      c1_compute(std::false_type{}, tid + 256, xin);
    }
    if (res) {
      float xin[4][6];
      c1_load(std::false_type{}, pos2, xin);
      c1_compute(std::false_type{}, pos2, xin);
    }
  } else {
    // edge strips (q=0: rows<0 possible; q=3: rows>127 / G=64 possible)
    {
      float xin0[4][6];
      c1_load(std::true_type{}, tid, xin0);
      c1_compute(std::true_type{}, tid, xin0);
    }
    {
      float xin[4][6];
      c1_load(std::true_type{}, tid + 256, xin);
      c1_compute(std::true_type{}, tid + 256, xin);
    }
    if (res) {
      float xin[4][6];
      c1_load(std::true_type{}, pos2, xin);
      c1_compute(std::true_type{}, pos2, xin);
    }
  }
  __syncthreads();  // B1: p1 (incl. halo zeros) ready

  // ---- conv2 (oc 0..3 packed as 2 f2 pairs) + ReLU + pool + sum ----
  const int px2  = tid & 31;
  const int py2l = tid >> 5;  // 0..7

  f2 acc[2][2][2];  // [ocpair p][dy][dx]
  {
    f2 bias0, bias1;
    bias0.x = b2[0]; bias0.y = b2[1];   // uniform -> s_load
    bias1.x = b2[2]; bias1.y = b2[3];
    acc[0][0][0] = bias0; acc[0][0][1] = bias0;
    acc[0][1][0] = bias0; acc[0][1][1] = bias0;
    acc[1][0][0] = bias1; acc[1][0][1] = bias1;
    acc[1][1][0] = bias1; acc[1][1][1] = bias1;
  }

  auto ld_xin = [&](int ic, float xin[4][4]) {
#pragma unroll
    for (int r = 0; r < 4; ++r) {
      // even 8B-aligned float2 reads — near-0 conflicts (r3)
      const f2* rp = (const f2*)&p1[ic][2 * py2l + r][2 * px2];
      f2 v0 = rp[0], v1 = rp[1];
      xin[r][0] = v0.x; xin[r][1] = v0.y; xin[r][2] = v1.x; xin[r][3] = v1.y;
    }
  };
  auto c2_acc = [&](int ic, const float xin[4][4]) {
#pragma unroll
    for (int ky = 0; ky < 3; ++ky)
#pragma unroll
      for (int kx = 0; kx < 3; ++kx) {
        const int k = ky * 3 + kx;
        f2 wA, wB;  // w2 layout [oc16][ic8][3][3]; uniform -> s_load
        wA.x = w2[0 * 72 + ic * 9 + k];
        wA.y = w2[1 * 72 + ic * 9 + k];
        wB.x = w2[2 * 72 + ic * 9 + k];
        wB.y = w2[3 * 72 + ic * 9 + k];
#pragma unroll
        for (int dy = 0; dy < 2; ++dy)
#pragma unroll
          for (int dx = 0; dx < 2; ++dx) {
            const f2 xs = splat2(xin[dy + ky][dx + kx]);
            acc[0][dy][dx] = fma2(wA, xs, acc[0][dy][dx]);
            acc[1][dy][dx] = fma2(wB, xs, acc[1][dy][dx]);
          }
      }
  };

  // Two named buffers; all indices static -> registers, never scratch.
  float xina[4][4], xinb[4][4];
  ld_xin(0, xina);
#pragma unroll 1
  for (int ic = 0; ic < 8; ic += 2) {
    ld_xin(ic + 1, xinb);              // issue under c2_acc(ic)
    c2_acc(ic, xina);
    if (ic < 6) ld_xin(ic + 2, xina);  // issue under c2_acc(ic+1)
    c2_acc(ic + 1, xinb);
  }

  // ---- ReLU + 2x2 pool + spatial partial-sum ----
  const int lane = tid & 63, w = tid >> 6;
#pragma unroll
  for (int p = 0; p < 2; ++p) {
    f2 m01;
    m01.x = fmaxf(fmaxf(fmaxf(acc[p][0][0].x, acc[p][0][1].x),
                        fmaxf(acc[p][1][0].x, acc[p][1][1].x)), 0.f);
    m01.y = fmaxf(fmaxf(fmaxf(acc[p][0][0].y, acc[p][0][1].y),
                        fmaxf(acc[p][1][0].y, acc[p][1][1].y)), 0.f);
#pragma unroll
    for (int off = 32; off > 0; off >>= 1) {
      m01.x += __shfl_down(m01.x, off);
      m01.y += __shfl_down(m01.y, off);
    }
    if (lane == 0) { wred[w][2 * p] = m01.x; wred[w][2 * p + 1] = m01.y; }
  }
  __syncthreads();
  if (tid < 4) {
    float s = wred[0][tid] + wred[1][tid] + wred[2][tid] + wred[3][tid];
    partials[((size_t)b * 4 + q) * 4 + tid] = s;
  }
}

// ---------------------------------------------------------------------------
// K3: feats -> quantum circuit -> batchnorm (over batch=512) -> head.
// Single block, 512 threads; thread = batch element. Shuffle reductions.
// ---------------------------------------------------------------------------
__global__ __launch_bounds__(512) void k3_tail(
    const float* __restrict__ partials, const float* __restrict__ qp,
    const float* __restrict__ gamma, const float* __restrict__ beta,
    const float* __restrict__ hw, const float* __restrict__ hb,
    float* __restrict__ out) {
  __shared__ float wsum[8][8];
  __shared__ float stats[8];
  const int tid = threadIdx.x;  // batch index

  const f4* pp = (const f4*)(partials + tid * 16);
  f4 s0 = pp[0], s1 = pp[1], s2 = pp[2], s3 = pp[3];
  float f[4];
  f[0] = (s0.x + s1.x + s2.x + s3.x) * (1.f / 1024.f);
  f[1] = (s0.y + s1.y + s2.y + s3.y) * (1.f / 1024.f);
  f[2] = (s0.z + s1.z + s2.z + s3.z) * (1.f / 1024.f);
  f[3] = (s0.w + s1.w + s2.w + s3.w) * (1.f / 1024.f);

  float a0r[4], a0i[4], a1r[4], a1i[4];
#pragma unroll
  for (int i = 0; i < 4; ++i) {
    float cy, sy, cx, sx;
    __sincosf(0.5f * f[i], &sy, &cy);
    __sincosf(0.5f * uload(qp + i), &sx, &cx);
    a0r[i] = cx * cy; a0i[i] = -sx * sy;
    a1r[i] = cx * sy; a1i[i] = -sx * cy;
  }

  float pr[16], pi[16];
#pragma unroll
  for (int j = 0; j < 16; ++j) {
    float rr = 1.f, ii = 0.f;
#pragma unroll
    for (int w = 0; w < 4; ++w) {
      int bit = (j >> (3 - w)) & 1;
      float ar = bit ? a1r[w] : a0r[w];
      float ai = bit ? a1i[w] : a0i[w];
      float t = rr * ar - ii * ai;
      ii = rr * ai + ii * ar;
      rr = t;
    }
    pr[j] = rr; pi[j] = ii;
  }

  constexpr int comp[16] = {0, 1, 3, 2, 6, 7, 5, 4, 12, 13, 15, 14, 10, 11, 9, 8};
  float qv[4] = {0.f, 0.f, 0.f, 0.f};
#pragma unroll
  for (int j = 0; j < 16; ++j) {
    int s = comp[j];
    float p = pr[s] * pr[s] + pi[s] * pi[s];
#pragma unroll
    for (int i = 0; i < 4; ++i)
      qv[i] += ((j >> (3 - i)) & 1) ? -p : p;
  }

  float v[8];
#pragma unroll
  for (int i = 0; i < 4; ++i) { v[i] = qv[i]; v[4 + i] = qv[i] * qv[i]; }
#pragma unroll
  for (int k = 0; k < 8; ++k)
#pragma unroll
    for (int off = 32; off > 0; off >>= 1) v[k] += __shfl_down(v[k], off);
  const int lane = tid & 63, w = tid >> 6;
  if (lane == 0) {
#pragma unroll
    for (int k = 0; k < 8; ++k) wsum[w][k] = v[k];
  }
  __syncthreads();
  if (tid < 8) {
    float s = 0.f;
#pragma unroll
    for (int ww = 0; ww < 8; ++ww) s += wsum[ww][tid];
    stats[tid] = s * (1.f / 512.f);
  }
  __syncthreads();

  float nm[4];
#pragma unroll
  for (int i = 0; i < 4; ++i) {
    float mu  = stats[i];
    float var = stats[4 + i] - mu * mu;
    nm[i] = uload(gamma + i) * (qv[i] - mu) * rsqrtf(var + EPS) + uload(beta + i);
  }
  f4 o4;
#pragma unroll
  for (int k = 0; k < 4; ++k) {
    float o = uload(hb + k);
#pragma unroll
    for (int i = 0; i < 4; ++i) o = fmaf(nm[i], uload(hw + k * 4 + i), o);
    o4[k] = o;
  }
  *(f4*)(out + tid * 4) = o4;  // 16B-aligned vector store, same values/order
}

extern "C" void kernel_launch(void* const* d_in, const int* in_sizes, int n_in,
                              void* d_out, int out_size, void* d_ws, size_t ws_size,
                              hipStream_t stream) {
  const float* x  = (const float*)d_in[0];
  const float* w1 = (const float*)d_in[1];
  const float* b1 = (const float*)d_in[2];
  const float* w2 = (const float*)d_in[3];
  const float* b2 = (const float*)d_in[4];
  const float* qp = (const float*)d_in[5];
  const float* gm = (const float*)d_in[6];
  const float* bt = (const float*)d_in[7];
  const float* hw = (const float*)d_in[8];
  const float* hb = (const float*)d_in[9];
  float* out = (float*)d_out;

  float* partials = (float*)d_ws;  // 512 * 4 strips * 4 oc floats = 32 KB

  k12_fused<<<512 * 4, 256, 0, stream>>>(x, w1, b1, w2, b2, partials);
  k3_tail<<<1, 512, 0, stream>>>(partials, qp, gm, bt, hw, hb, out);
}

// Round 12
// 117.488 us; speedup vs baseline: 1.0398x; 1.0398x over previous
//
#include <hip/hip_runtime.h>

#define EPS 1e-5f

typedef float f2 __attribute__((ext_vector_type(2)));
typedef float f4 __attribute__((ext_vector_type(4)));

// Broadcast a block-uniform load into an SGPR (scalars).
__device__ __forceinline__ float uload(const float* __restrict__ p) {
  return __int_as_float(__builtin_amdgcn_readfirstlane(__float_as_int(*p)));
}

__device__ __forceinline__ f2 fma2(f2 a, f2 b, f2 c) {
  return __builtin_elementwise_fma(a, b, c);
}
__device__ __forceinline__ f2 splat2(float s) { f2 r; r.x = s; r.y = s; return r; }

// ---------------------------------------------------------------------------
// K12: fused conv1(1->8)+ReLU+pool + conv2(4 used oc of 16)+ReLU+pool + sum.
// Block = (batch b, quarter q): pooled2 rows 8q..8q+7, 256 threads.
// == r16/r20 structure: best passing, 117.9 us, reconfirmed twice ==
// Final session map (r1-r22):
//  - conv1 reads x from GLOBAL. LDS xtile stride-2 reads = 1.06M conflict
//    cycles (r4). Never again.
//  - conv1 REGISTER prefetch PERMANENTLY DEAD: r9/r11/r13/r15/r17 all
//    spilled. 64-VGPR allocator target immovable (amdgpu_waves_per_eu
//    did nothing). Live state <= ONE 24-float xin buffer.
//  - r16: weights block-uniform -> SGPRs (s_load via scalar cache, zero
//    VGPR cost). Freed 36 VGPRs, removed LDS staging + barrier + ~30K
//    ds_read/block. BEST: 117.9 us (reconfirmed r20).
//  - r18: 576-thr one-task-per-thread regressed (no intra-thread overlap).
//  - r19: width-32 __shfl halo DIVERGED under graph replay. BANNED.
//  - r21: interior/edge constexpr split + residue spread regressed
//    (+4 us): doubled conv1 I-footprint + divergent residue branch.
//    Wave-uniform branches are not free when they duplicate hot code.
//  - r14: occupancy NOT LDS-limited; per-block fixed cost dominates.
//  - r15: never hold xin across the conv2 phase (119 MB spill).
//  - pk_fma (r7) + conv2 two-named-buffer ic pipeline (r12) keepers.
//  - r10: tail fusion = ~30 us serialization; tail stays separate.
//    Harness d_ws fill (~44 us) + input restore (~11 us) are fixed.
//  - Ceiling analysis: k12 ~38 us vs ~8 us FLOP floor; the gap is
//    unhidden global latency closable only by register pipelining,
//    which the 64-VGPR wall forbids at this shape. Practical optimum.
// ---------------------------------------------------------------------------
__global__ __launch_bounds__(256, 4) void k12_fused(
    const float* __restrict__ x, const float* __restrict__ w1,
    const float* __restrict__ b1, const float* __restrict__ w2,
    const float* __restrict__ b2, float* __restrict__ partials) {
  __shared__ __align__(16) float p1[8][18][66];  // pooled1; col idx = col+1
  __shared__ float wred[4][4];

  const int q   = blockIdx.x & 3;
  const int b   = blockIdx.x >> 2;
  const int tid = threadIdx.x;
  const float* xb = x + (size_t)b * (128 * 128);

  auto c1_load = [&](int pos, float xin[4][6]) {
    const int gl = pos >> 5, i = pos & 31;
    const int G  = 16 * q - 1 + gl;
    const bool vG = ((unsigned)G) < 64u;
    const int xr0 = 2 * G - 1;
#pragma unroll
    for (int r = 0; r < 4; ++r) {
      const int row  = xr0 + r;
      const bool rok = vG && ((unsigned)row < 128u);
      const int rowc = min(max(row, 0), 127);
      const float* rp = xb + rowc * 128;
      const float le = rp[(i == 0) ? 0 : (4 * i - 1)];
      const f4 mid   = *(const f4*)(rp + 4 * i);        // 16B-aligned
      const float ri = rp[(i == 31) ? 127 : (4 * i + 4)];
      xin[r][0] = (rok && i != 0)  ? le    : 0.f;
      xin[r][1] = rok              ? mid.x : 0.f;
      xin[r][2] = rok              ? mid.y : 0.f;
      xin[r][3] = rok              ? mid.z : 0.f;
      xin[r][4] = rok              ? mid.w : 0.f;
      xin[r][5] = (rok && i != 31) ? ri    : 0.f;
    }
  };
  auto c1_compute = [&](int pos, const float xin[4][6]) {
    const int gl = pos >> 5, i = pos & 31;
    const int G  = 16 * q - 1 + gl;
    const bool vG = ((unsigned)G) < 64u;
    // Two sequential oc-halves; weights are UNIFORM scalar loads (SGPRs).
#pragma unroll 1
    for (int g = 0; g < 2; ++g) {
      f2 wpx[9][2], bias[2];
#pragma unroll
      for (int k = 0; k < 9; ++k)
#pragma unroll
        for (int p = 0; p < 2; ++p) {
          const int oc = 4 * g + 2 * p;
          f2 wv;
          wv.x = w1[oc * 9 + k];        // uniform -> s_load
          wv.y = w1[(oc + 1) * 9 + k];  // uniform -> s_load
          wpx[k][p] = wv;
        }
      bias[0].x = b1[4 * g];     bias[0].y = b1[4 * g + 1];
      bias[1].x = b1[4 * g + 2]; bias[1].y = b1[4 * g + 3];
#pragma unroll
      for (int p = 0; p < 2; ++p)
#pragma unroll
        for (int h = 0; h < 2; ++h) {  // pooled col 2i+h
          f2 best = splat2(0.f);       // ReLU floor
#pragma unroll
          for (int dy = 0; dy < 2; ++dy)
#pragma unroll
            for (int dx = 0; dx < 2; ++dx) {
              f2 a = bias[p];
#pragma unroll
              for (int ky = 0; ky < 3; ++ky)
#pragma unroll
                for (int kx = 0; kx < 3; ++kx)
                  a = fma2(wpx[ky * 3 + kx][p],
                           splat2(xin[dy + ky][2 * h + dx + kx]), a);
              best.x = fmaxf(best.x, a.x);
              best.y = fmaxf(best.y, a.y);
            }
          const int oc0 = 4 * g + 2 * p;
          p1[oc0][gl][2 * i + 1 + h]     = vG ? best.x : 0.f;
          p1[oc0 + 1][gl][2 * i + 1 + h] = vG ? best.y : 0.f;
        }
    }
  };

  // zero p1's SAME-padding halo columns (disjoint from conv1's writes;
  // ordered vs conv2's reads by B1 — no extra barrier needed)
  if (tid >= 96 && tid < 240) {
    int t = tid - 96;
    int ic = t / 18, r = t % 18;
    p1[ic][r][0]  = 0.f;
    p1[ic][r][65] = 0.f;
  }

  // ---- conv1 + ReLU + pool, ALL 8 channels; task-0 loads hoisted ----
  {
    float xin0[4][6];
    c1_load(tid, xin0);
    c1_compute(tid, xin0);
  }
#pragma unroll 1
  for (int pos = tid + 256; pos < 576; pos += 256) {
    float xin[4][6];
    c1_load(pos, xin);
    c1_compute(pos, xin);
  }
  __syncthreads();  // B1: p1 (incl. halo zeros) ready

  // ---- conv2 (oc 0..3 packed as 2 f2 pairs) + ReLU + pool + sum ----
  const int px2  = tid & 31;
  const int py2l = tid >> 5;  // 0..7

  f2 acc[2][2][2];  // [ocpair p][dy][dx]
  {
    f2 bias0, bias1;
    bias0.x = b2[0]; bias0.y = b2[1];   // uniform -> s_load
    bias1.x = b2[2]; bias1.y = b2[3];
    acc[0][0][0] = bias0; acc[0][0][1] = bias0;
    acc[0][1][0] = bias0; acc[0][1][1] = bias0;
    acc[1][0][0] = bias1; acc[1][0][1] = bias1;
    acc[1][1][0] = bias1; acc[1][1][1] = bias1;
  }

  auto ld_xin = [&](int ic, float xin[4][4]) {
#pragma unroll
    for (int r = 0; r < 4; ++r) {
      // even 8B-aligned float2 reads — near-0 conflicts (r3)
      const f2* rp = (const f2*)&p1[ic][2 * py2l + r][2 * px2];
      f2 v0 = rp[0], v1 = rp[1];
      xin[r][0] = v0.x; xin[r][1] = v0.y; xin[r][2] = v1.x; xin[r][3] = v1.y;
    }
  };
  auto c2_acc = [&](int ic, const float xin[4][4]) {
#pragma unroll
    for (int ky = 0; ky < 3; ++ky)
#pragma unroll
      for (int kx = 0; kx < 3; ++kx) {
        const int k = ky * 3 + kx;
        f2 wA, wB;  // w2 layout [oc16][ic8][3][3]; uniform -> s_load
        wA.x = w2[0 * 72 + ic * 9 + k];
        wA.y = w2[1 * 72 + ic * 9 + k];
        wB.x = w2[2 * 72 + ic * 9 + k];
        wB.y = w2[3 * 72 + ic * 9 + k];
#pragma unroll
        for (int dy = 0; dy < 2; ++dy)
#pragma unroll
          for (int dx = 0; dx < 2; ++dx) {
            const f2 xs = splat2(xin[dy + ky][dx + kx]);
            acc[0][dy][dx] = fma2(wA, xs, acc[0][dy][dx]);
            acc[1][dy][dx] = fma2(wB, xs, acc[1][dy][dx]);
          }
      }
  };

  // Two named buffers; all indices static -> registers, never scratch.
  float xina[4][4], xinb[4][4];
  ld_xin(0, xina);
#pragma unroll 1
  for (int ic = 0; ic < 8; ic += 2) {
    ld_xin(ic + 1, xinb);              // issue under c2_acc(ic)
    c2_acc(ic, xina);
    if (ic < 6) ld_xin(ic + 2, xina);  // issue under c2_acc(ic+1)
    c2_acc(ic + 1, xinb);
  }

  // ---- ReLU + 2x2 pool + spatial partial-sum ----
  const int lane = tid & 63, w = tid >> 6;
#pragma unroll
  for (int p = 0; p < 2; ++p) {
    f2 m01;
    m01.x = fmaxf(fmaxf(fmaxf(acc[p][0][0].x, acc[p][0][1].x),
                        fmaxf(acc[p][1][0].x, acc[p][1][1].x)), 0.f);
    m01.y = fmaxf(fmaxf(fmaxf(acc[p][0][0].y, acc[p][0][1].y),
                        fmaxf(acc[p][1][0].y, acc[p][1][1].y)), 0.f);
#pragma unroll
    for (int off = 32; off > 0; off >>= 1) {
      m01.x += __shfl_down(m01.x, off);
      m01.y += __shfl_down(m01.y, off);
    }
    if (lane == 0) { wred[w][2 * p] = m01.x; wred[w][2 * p + 1] = m01.y; }
  }
  __syncthreads();
  if (tid < 4) {
    float s = wred[0][tid] + wred[1][tid] + wred[2][tid] + wred[3][tid];
    partials[((size_t)b * 4 + q) * 4 + tid] = s;
  }
}

// ---------------------------------------------------------------------------
// K3: feats -> quantum circuit -> batchnorm (over batch=512) -> head.
// Single block, 512 threads; thread = batch element. Shuffle reductions.
// ---------------------------------------------------------------------------
__global__ __launch_bounds__(512) void k3_tail(
    const float* __restrict__ partials, const float* __restrict__ qp,
    const float* __restrict__ gamma, const float* __restrict__ beta,
    const float* __restrict__ hw, const float* __restrict__ hb,
    float* __restrict__ out) {
  __shared__ float wsum[8][8];
  __shared__ float stats[8];
  const int tid = threadIdx.x;  // batch index

  const f4* pp = (const f4*)(partials + tid * 16);
  f4 s0 = pp[0], s1 = pp[1], s2 = pp[2], s3 = pp[3];
  float f[4];
  f[0] = (s0.x + s1.x + s2.x + s3.x) * (1.f / 1024.f);
  f[1] = (s0.y + s1.y + s2.y + s3.y) * (1.f / 1024.f);
  f[2] = (s0.z + s1.z + s2.z + s3.z) * (1.f / 1024.f);
  f[3] = (s0.w + s1.w + s2.w + s3.w) * (1.f / 1024.f);

  float a0r[4], a0i[4], a1r[4], a1i[4];
#pragma unroll
  for (int i = 0; i < 4; ++i) {
    float cy, sy, cx, sx;
    __sincosf(0.5f * f[i], &sy, &cy);
    __sincosf(0.5f * uload(qp + i), &sx, &cx);
    a0r[i] = cx * cy; a0i[i] = -sx * sy;
    a1r[i] = cx * sy; a1i[i] = -sx * cy;
  }

  float pr[16], pi[16];
#pragma unroll
  for (int j = 0; j < 16; ++j) {
    float rr = 1.f, ii = 0.f;
#pragma unroll
    for (int w = 0; w < 4; ++w) {
      int bit = (j >> (3 - w)) & 1;
      float ar = bit ? a1r[w] : a0r[w];
      float ai = bit ? a1i[w] : a0i[w];
      float t = rr * ar - ii * ai;
      ii = rr * ai + ii * ar;
      rr = t;
    }
    pr[j] = rr; pi[j] = ii;
  }

  constexpr int comp[16] = {0, 1, 3, 2, 6, 7, 5, 4, 12, 13, 15, 14, 10, 11, 9, 8};
  float qv[4] = {0.f, 0.f, 0.f, 0.f};
#pragma unroll
  for (int j = 0; j < 16; ++j) {
    int s = comp[j];
    float p = pr[s] * pr[s] + pi[s] * pi[s];
#pragma unroll
    for (int i = 0; i < 4; ++i)
      qv[i] += ((j >> (3 - i)) & 1) ? -p : p;
  }

  float v[8];
#pragma unroll
  for (int i = 0; i < 4; ++i) { v[i] = qv[i]; v[4 + i] = qv[i] * qv[i]; }
#pragma unroll
  for (int k = 0; k < 8; ++k)
#pragma unroll
    for (int off = 32; off > 0; off >>= 1) v[k] += __shfl_down(v[k], off);
  const int lane = tid & 63, w = tid >> 6;
  if (lane == 0) {
#pragma unroll
    for (int k = 0; k < 8; ++k) wsum[w][k] = v[k];
  }
  __syncthreads();
  if (tid < 8) {
    float s = 0.f;
#pragma unroll
    for (int ww = 0; ww < 8; ++ww) s += wsum[ww][tid];
    stats[tid] = s * (1.f / 512.f);
  }
  __syncthreads();

  float nm[4];
#pragma unroll
  for (int i = 0; i < 4; ++i) {
    float mu  = stats[i];
    float var = stats[4 + i] - mu * mu;
    nm[i] = uload(gamma + i) * (qv[i] - mu) * rsqrtf(var + EPS) + uload(beta + i);
  }
  f4 o4;
#pragma unroll
  for (int k = 0; k < 4; ++k) {
    float o = uload(hb + k);
#pragma unroll
    for (int i = 0; i < 4; ++i) o = fmaf(nm[i], uload(hw + k * 4 + i), o);
    o4[k] = o;
  }
  *(f4*)(out + tid * 4) = o4;  // 16B-aligned vector store, same values/order
}

extern "C" void kernel_launch(void* const* d_in, const int* in_sizes, int n_in,
                              void* d_out, int out_size, void* d_ws, size_t ws_size,
                              hipStream_t stream) {
  const float* x  = (const float*)d_in[0];
  const float* w1 = (const float*)d_in[1];
  const float* b1 = (const float*)d_in[2];
  const float* w2 = (const float*)d_in[3];
  const float* b2 = (const float*)d_in[4];
  const float* qp = (const float*)d_in[5];
  const float* gm = (const float*)d_in[6];
  const float* bt = (const float*)d_in[7];
  const float* hw = (const float*)d_in[8];
  const float* hb = (const float*)d_in[9];
  float* out = (float*)d_out;

  float* partials = (float*)d_ws;  // 512 * 4 strips * 4 oc floats = 32 KB

  k12_fused<<<512 * 4, 256, 0, stream>>>(x, w1, b1, w2, b2, partials);
  k3_tail<<<1, 512, 0, stream>>>(partials, qp, gm, bt, hw, hb, out);
}